// Round 3
// baseline (143.175 us; speedup 1.0000x reference)
//
#include <hip/hip_runtime.h>

// out[i,j] = sum_d x[i,d] * Weff[j,d] + b[j]
// Weff[j,d] = W[j,d] + sum_k M[k,d] * W[j, 42+k],  M = connect-4 window masks
// (incl. the reference's bugs: diag windows are full 4x4 blocks; features
// 57..68 have zero masks).

#define ROW_PAD 43   // 42+1: stride 43 across lanes -> 2 lanes/bank = free

__global__ __launch_bounds__(320)
void ddqn_weff(const float* __restrict__ W, float* __restrict__ weff) {
    int tid = threadIdx.x;
    if (tid >= 7 * 42) return;
    int j = tid / 42;
    int d = tid % 42;
    float acc = W[j * 111 + d];
    int r = d / 7, c = d % 7;
    const float* ws = W + j * 111 + 42;
    for (int i = 0; i < 4; ++i)                      // 24 row windows
        if (c >= i && c <= i + 3) acc += ws[r * 4 + i];
    for (int i = 0; i < 3; ++i)                      // 21 col windows
        if (r >= i && r <= i + 3) acc += ws[24 + c * 3 + i];
    for (int off = 0; off < 3; ++off)                // 12 "diag" (full 4x4 bug)
        for (int col = 0; col < 4; ++col)
            if (r >= 2 - off && r <= 5 - off && c >= col && c <= col + 3)
                acc += ws[45 + off * 4 + col];
    weff[j * 42 + d] = acc;                          // feats 57..68: zero masks
}

// 256 threads = 4 waves; each wave owns a private 64-row tile. No block
// barriers after the one-time weight stage -> waves pipeline independently.
__global__ __launch_bounds__(256)
void ddqn_main(const float* __restrict__ gs,
               const float* __restrict__ weff,
               const float* __restrict__ b,
               float* __restrict__ out) {
    __shared__ float wl[7 * 44 + 8];              // weights [7][44] pad + bias
    __shared__ float tile[4][64 * ROW_PAD];       // per-wave 64x43 slabs

    const int t = threadIdx.x;
    // One-time cooperative weight+bias stage (only block-wide sync point).
    for (int i = t; i < 7 * 44; i += 256) {
        int j = i / 44, d = i % 44;
        wl[i] = (d < 42) ? weff[j * 42 + d] : 0.0f;
    }
    if (t < 7) wl[7 * 44 + t] = b[t];
    __syncthreads();

    const int w = t >> 6;
    const int l = t & 63;
    float* tw = tile[w];

    const size_t tileIdx = (size_t)blockIdx.x * 4 + w;   // 64-row tile per wave
    const float* src = gs + tileIdx * (64 * 42);

    // Stage: f = k*64 + l. Global: 64 consecutive lanes -> 256B/instr,
    // perfectly coalesced. LDS: addresses consecutive (+1 at row crossings)
    // -> <=3 lanes/bank, ~free.
    int row = l / 42;                // 0 or 1
    int col = l - row * 42;
    #pragma unroll
    for (int k = 0; k < 42; ++k) {
        tw[row * ROW_PAD + col] = src[k * 64 + l];
        row += 1; col += 22;         // advance f by 64 = 1*42 + 22
        if (col >= 42) { col -= 42; row += 1; }
    }
    // Intra-wave RAW through LDS: DS ops complete in-order within a wave, so
    // no s_waitcnt/barrier needed; this only fences the compiler scheduler.
    __builtin_amdgcn_wave_barrier();

    float acc[7];
    #pragma unroll
    for (int j = 0; j < 7; ++j) acc[j] = wl[7 * 44 + j];

    const float* xrow = tw + l * ROW_PAD;
    const float4* wl4 = (const float4*)wl;
    #pragma unroll
    for (int dq = 0; dq < 44; dq += 4) {
        // x: scalar LDS reads, stride 43 across lanes (2 lanes/bank = free)
        float x0 = xrow[dq];
        float x1 = xrow[dq + 1];
        float x2 = (dq + 2 < 42) ? xrow[dq + 2] : 0.0f;
        float x3 = (dq + 3 < 42) ? xrow[dq + 3] : 0.0f;
        #pragma unroll
        for (int j = 0; j < 7; ++j) {
            // wave-uniform address -> conflict-free LDS broadcast
            const float4 wv = wl4[j * 11 + (dq >> 2)];
            acc[j] = fmaf(x0, wv.x, acc[j]);
            acc[j] = fmaf(x1, wv.y, acc[j]);
            acc[j] = fmaf(x2, wv.z, acc[j]);
            acc[j] = fmaf(x3, wv.w, acc[j]);
        }
    }

    float* o = out + (tileIdx * 64 + l) * 7;
    #pragma unroll
    for (int j = 0; j < 7; ++j) o[j] = acc[j];
}

extern "C" void kernel_launch(void* const* d_in, const int* in_sizes, int n_in,
                              void* d_out, int out_size, void* d_ws, size_t ws_size,
                              hipStream_t stream) {
    const float* gs = (const float*)d_in[0];   // [B, 42] f32
    const float* W  = (const float*)d_in[1];   // [7, 111] f32
    const float* b  = (const float*)d_in[2];   // [7] f32
    float* out  = (float*)d_out;               // [B, 7] f32
    float* weff = (float*)d_ws;                // [7, 42] f32 scratch

    ddqn_weff<<<dim3(1), dim3(320), 0, stream>>>(W, weff);

    int B = in_sizes[0] / 42;                  // 524288
    int tiles = B / 64;                        // 8192 wave-tiles
    ddqn_main<<<dim3(tiles / 4), dim3(256), 0, stream>>>(gs, weff, b, out);
}